// Round 5
// baseline (296.170 us; speedup 1.0000x reference)
//
#include <hip/hip_runtime.h>

// Correlation layer: out[b, dy*9+dx, y, x] =
//   (1/256) * sum_c frn[b,c,y,x] * fqn_pad[b,c,y+dy,x+dx]   (pad r=4)
// Identity: dot(frn,fqn) = dot(fr,fq) * invnorm(fr) * invnorm(fq).
//
// R12: R11 main loop VERBATIM per wave + 2-way CHANNEL SPLIT across waves.
// R11 post-mortem: traffic fix worked (0.8GB fabric, 5.2 TB/s) but grid
// shrank 3x -> 1152 waves = 1.1 waves/SIMD (Occupancy 11%). Per-chunk wall
// 5775 cyc vs ~1750 cyc issue demand => ~4000 cyc naked ds_read->FMA
// latency per chunk; single wave/SIMD can't hide it (VALUBusy 32%).
// Fix: 2 waves/block; wave w owns channels [128w,128w+128) = 32 chunks,
// with its OWN double-buffered LDS pair s_fq[wid][p] and own counted
// vmcnt(11) (per-wave counters -> waves fully independent, 0 in-loop
// barriers). Traffic unchanged (every byte still fetched once); waves
// double to 2304 = 2.25/SIMD. Partials (acc/sqn/fr2) combined at the end
// by a 2-round LDS reduction REUSING the drained staging buffers
// (round1: acc 27 f4/lane = 1728 slots = exactly the staging size;
// round2: sqn 9 f4 + fr2 1 f4); wave 0 runs the epilogue.
// Steady-state VMEM queue at each vmcnt(11) (per wave, oldest->newest):
//   [this buf's 7 DMAs][4 fr rolls][other buf's 7 DMAs] = 18 outstanding
//   -> vmcnt(11) drains exactly this buffer's DMAs.
// DMA count runtime-uniform (7/iter); OOB halo lanes CLAMP-addressed;
// zero-pad semantics via epilogue mask.

#define BB 8
#define CC 256
#define HH 96
#define WW 128
#define HW (HH*WW)
#define CHW (CC*HW)
#define NDISP 81
#define TYS 4            // output rows per block
#define GD 3             // dy per block
#define HROWS (TYS+GD-1) // 6 staged rows per chunk-channel
#define HX4 18           // halo row width in float4 (72 floats = 64 + 8)
#define NSLOT (HROWS*HX4) // 108 float4 slots per channel
#define CK 4             // channels per chunk
#define CKHW (CK*HW)
#define NW 2             // waves per block (channel split)
#define NCHW (CC/(CK*NW)) // 32 chunks per wave
#define NST (NSLOT*CK)   // 432 float4 slots per chunk
#define YT (HH/TYS)      // 24
#define XT 2
#define NTILES (BB*YT*XT) // 384
#define NGRP 3           // dy-groups
#define EPSN 1e-12f

__device__ __forceinline__ void dma16(const void* g, void* l) {
    __builtin_amdgcn_global_load_lds(
        (const __attribute__((address_space(1))) void*)g,
        (__attribute__((address_space(3))) void*)l,
        16, 0, 0);
}

__global__ __launch_bounds__(128) __attribute__((amdgpu_waves_per_eu(2, 8)))
void corr_kernel(
    const float* __restrict__ fr, const float* __restrict__ fq,
    float* __restrict__ out)
{
    __shared__ float4 s_fq[NW][2][NST];   // 27648 B: per-wave double buffer

    const int lane = threadIdx.x & 63;
    const int wid  = threadIdx.x >> 6;    // 0..1: channel-half owner
    const int tx   = lane & 15;    // 0..15, 4 px each
    const int ty   = lane >> 4;    // 0..3

    const int tile = blockIdx.x % NTILES;  // dyg-copies at stride 384 ≡ 0 mod 8 → same XCD
    const int dyg  = blockIdx.x / NTILES;  // 0..2 → dy = 3*dyg + g
    const int b    = tile / (YT * XT);
    const int rem  = tile % (YT * XT);
    const int y0   = (rem >> 1) * TYS;
    const int x0   = (rem & 1) * 64;

    const int cbase = wid * (NCHW * CKHW); // this wave's channel base offset

    // ---- staging addresses: slot i = 64j+lane -> (c=i/108, row=(i%108)/18, col4=i%18)
    // OOB rows/cols clamped to valid addresses (garbage data; masked at epilogue).
    int soff[7];
#pragma unroll
    for (int j = 0; j < 7; ++j) {
        int i = 64 * j + lane;
        int c    = (i / NSLOT) & 3;   // &3: j=6 upper lanes never DMA'd, keep addr safe
        int s    = i % NSLOT;
        int row  = s / HX4;
        int col4 = s % HX4;
        int gy = y0 + 3 * dyg - 4 + row;
        int gx = x0 - 4 + col4 * 4;
        gy = min(max(gy, 0), HH - 1);
        gx = min(max(gx, 0), WW - 4);   // stays 16B-aligned
        soff[j] = b * CHW + cbase + c * HW + gy * WW + gx;
    }

    const int frbase = b * CHW + cbase + (y0 + ty) * WW + x0 + tx * 4;

    // ---- preamble: DMA chunk 0 -> buf0 (7 events), fr chunk 0 -> regs (4 events)
#pragma unroll
    for (int j = 0; j < 6; ++j)
        dma16(fq + soff[j], &s_fq[wid][0][64 * j]);
    if (lane < 48)                       // 48 tail slots; exec never empty
        dma16(fq + soff[6], &s_fq[wid][0][384]);

    float4 fra[CK];
#pragma unroll
    for (int c = 0; c < CK; ++c)
        fra[c] = *(const float4*)(fr + frbase + c * HW);

    float4 acc[GD][9];
#pragma unroll
    for (int g = 0; g < GD; ++g)
#pragma unroll
        for (int d = 0; d < 9; ++d) acc[g][d] = make_float4(0.f, 0.f, 0.f, 0.f);
    float sqn[GD][12];
#pragma unroll
    for (int g = 0; g < GD; ++g)
#pragma unroll
        for (int i = 0; i < 12; ++i) sqn[g][i] = 0.f;
    float4 fr2 = make_float4(0.f, 0.f, 0.f, 0.f);

#pragma unroll 1
    for (int ch = 0; ch < NCHW; ++ch) {
        const int p   = ch & 1;
        const int nch = (ch + 1 < NCHW) ? ch + 1 : ch;   // last iter: dead re-issue
        const int nco = nch * CKHW;                      // keeps vmcnt count uniform

        // ---- issue next chunk's 7 DMAs into the other buffer ----
#pragma unroll
        for (int j = 0; j < 6; ++j)
            dma16(fq + soff[j] + nco, &s_fq[wid][1 - p][64 * j]);
        if (lane < 48)
            dma16(fq + soff[6] + nco, &s_fq[wid][1 - p][384]);

        // Drain everything older than the 11 just/soon-issued next-chunk ops:
        // prev 7 DMA (this chunk's fq) done; prev 4 fr covered by reg deps.
        __builtin_amdgcn_s_waitcnt(0x0F7B);   // vmcnt(11), no lgkm/exp wait
        __builtin_amdgcn_sched_barrier(0);    // nothing hoists above the wait

        // ---- compute 4 channels x 3 dy from buf p; roll fr one chunk ahead ----
#pragma unroll
        for (int c = 0; c < CK; ++c) {
            float4 a = fra[c];
            fra[c] = *(const float4*)(fr + frbase + nco + c * HW);
            fr2.x += a.x * a.x; fr2.y += a.y * a.y;
            fr2.z += a.z * a.z; fr2.w += a.w * a.w;

#pragma unroll
            for (int g = 0; g < GD; ++g) {
                float rw[12];
#pragma unroll
                for (int s4 = 0; s4 < 3; ++s4) {
                    float4 t = s_fq[wid][p][c * NSLOT + (ty + g) * HX4 + tx + s4];
                    rw[s4 * 4 + 0] = t.x;
                    rw[s4 * 4 + 1] = t.y;
                    rw[s4 * 4 + 2] = t.z;
                    rw[s4 * 4 + 3] = t.w;
                }
#pragma unroll
                for (int i = 0; i < 12; ++i) sqn[g][i] += rw[i] * rw[i];
#pragma unroll
                for (int dx = 0; dx < 9; ++dx) {
                    acc[g][dx].x += a.x * rw[dx + 0];
                    acc[g][dx].y += a.y * rw[dx + 1];
                    acc[g][dx].z += a.z * rw[dx + 2];
                    acc[g][dx].w += a.w * rw[dx + 3];
                }
            }
        }
    }

    // drain dead-issued DMAs (own wave's) before staging LDS is reused
    __builtin_amdgcn_s_waitcnt(0x0F70);   // vmcnt(0)

    // ---- cross-wave reduction: reuse drained staging LDS (1728 f4 slots) ----
    float4* red = &s_fq[0][0][0];
    __syncthreads();
    if (wid) {                       // round 1: acc[3][9] = 27 f4/lane
#pragma unroll
        for (int g = 0; g < GD; ++g)
#pragma unroll
            for (int d = 0; d < 9; ++d)
                red[lane * 27 + g * 9 + d] = acc[g][d];
    }
    __syncthreads();
    if (!wid) {
#pragma unroll
        for (int g = 0; g < GD; ++g)
#pragma unroll
            for (int d = 0; d < 9; ++d) {
                float4 t = red[lane * 27 + g * 9 + d];
                acc[g][d].x += t.x; acc[g][d].y += t.y;
                acc[g][d].z += t.z; acc[g][d].w += t.w;
            }
    }
    __syncthreads();
    if (wid) {                       // round 2: sqn (9 f4) + fr2 (1 f4)
#pragma unroll
        for (int g = 0; g < GD; ++g)
#pragma unroll
            for (int i = 0; i < 3; ++i)
                red[lane * 10 + g * 3 + i] = make_float4(
                    sqn[g][4*i+0], sqn[g][4*i+1], sqn[g][4*i+2], sqn[g][4*i+3]);
        red[lane * 10 + 9] = fr2;
    }
    __syncthreads();
    if (wid) return;                 // wave 0 finishes

#pragma unroll
    for (int g = 0; g < GD; ++g)
#pragma unroll
        for (int i = 0; i < 3; ++i) {
            float4 t = red[lane * 10 + g * 3 + i];
            sqn[g][4*i+0] += t.x; sqn[g][4*i+1] += t.y;
            sqn[g][4*i+2] += t.z; sqn[g][4*i+3] += t.w;
        }
    {
        float4 t = red[lane * 10 + 9];
        fr2.x += t.x; fr2.y += t.y; fr2.z += t.z; fr2.w += t.w;
    }

    // ---- epilogue: norms in registers + OOB mask (== reference zero-pad) ----
    float4 ir;
    ir.x = 1.0f / fmaxf(sqrtf(fr2.x), EPSN);
    ir.y = 1.0f / fmaxf(sqrtf(fr2.y), EPSN);
    ir.z = 1.0f / fmaxf(sqrtf(fr2.z), EPSN);
    ir.w = 1.0f / fmaxf(sqrtf(fr2.w), EPSN);

    const int  xe0   = x0 + tx * 4;
    const float inv256 = 1.0f / 256.0f;

#pragma unroll
    for (int g = 0; g < GD; ++g) {
        const int dy = 3 * dyg + g;
        float inq[12];
#pragma unroll
        for (int i = 0; i < 12; ++i)
            inq[i] = 1.0f / fmaxf(sqrtf(sqn[g][i]), EPSN);

        const bool rowok = ((unsigned)(y0 + ty + dy - 4) < (unsigned)HH);
        const int obase = (b * NDISP + dy * 9) * HW + (y0 + ty) * WW + xe0;
#pragma unroll
        for (int dx = 0; dx < 9; ++dx) {
            float4 a = acc[g][dx];
            float4 o;
            o.x = a.x * ir.x * inq[dx + 0] * inv256;
            o.y = a.y * ir.y * inq[dx + 1] * inv256;
            o.z = a.z * ir.z * inq[dx + 2] * inv256;
            o.w = a.w * ir.w * inq[dx + 3] * inv256;
            const int cb = xe0 + dx - 4;   // fq column for px .x at this dx
            o.x = (rowok && (unsigned)(cb    ) < (unsigned)WW) ? o.x : 0.f;
            o.y = (rowok && (unsigned)(cb + 1) < (unsigned)WW) ? o.y : 0.f;
            o.z = (rowok && (unsigned)(cb + 2) < (unsigned)WW) ? o.z : 0.f;
            o.w = (rowok && (unsigned)(cb + 3) < (unsigned)WW) ? o.w : 0.f;
            *(float4*)(out + obase + dx * HW) = o;
        }
    }
}

extern "C" void kernel_launch(void* const* d_in, const int* in_sizes, int n_in,
                              void* d_out, int out_size, void* d_ws, size_t ws_size,
                              hipStream_t stream) {
    const float* fr = (const float*)d_in[0];
    const float* fq = (const float*)d_in[1];
    float* out = (float*)d_out;
    corr_kernel<<<dim3(NTILES * NGRP), dim3(128), 0, stream>>>(fr, fq, out);
}